// Round 1
// baseline (5766.141 us; speedup 1.0000x reference)
//
#include <hip/hip_runtime.h>

#define B_ 16384
#define T_ 60
#define H_ 128

typedef unsigned short u16;
typedef short bf16x8 __attribute__((ext_vector_type(8)));
typedef float f32x4 __attribute__((ext_vector_type(4)));

__device__ __forceinline__ u16 f2bf(float f) {
  union { float f; unsigned int u; } v; v.f = f;
  unsigned int r = v.u + 0x7fffu + ((v.u >> 16) & 1u);
  return (u16)(r >> 16);
}
__device__ __forceinline__ float bf2f(u16 b) {
  union { unsigned int u; float f; } v; v.u = ((unsigned int)b) << 16;
  return v.f;
}
__device__ __forceinline__ float sigm(float x) {
  return __builtin_amdgcn_rcpf(1.f + __expf(-x));
}
__device__ __forceinline__ float tanh_f(float x) {
  return 1.f - 2.f * __builtin_amdgcn_rcpf(1.f + __expf(2.f * x));
}

// ---------------------------------------------------------------------------
// prep: pack weights into MFMA B-fragment order with gate permutation n=j*4+g,
// fold biases, fold Wout@Wlat -> Wco/bco.
// wfrag element ((c*32+gnt)*64+lane)*8+j  = W[k = c*32+(lane>>4)*8+j][n = gnt*16+(lane&15)]
// ---------------------------------------------------------------------------
__global__ void prep_kernel(const float* __restrict__ Wih1, const float* __restrict__ Whh1,
                            const float* __restrict__ bih1, const float* __restrict__ bhh1,
                            const float* __restrict__ Wih2, const float* __restrict__ Whh2,
                            const float* __restrict__ bih2, const float* __restrict__ bhh2,
                            const float* __restrict__ Wlat, const float* __restrict__ blat,
                            const float* __restrict__ Wout, const float* __restrict__ bout,
                            u16* __restrict__ wfrag1, u16* __restrict__ wfrag2,
                            float* __restrict__ biasp1, float* __restrict__ biasp2,
                            float* __restrict__ Wco, float* __restrict__ bco) {
  const int N1 = 9 * 32 * 64;   // 18432 lane-groups of 8
  const int N2 = 8 * 32 * 64;   // 16384
  const int total = N1 + N2 + 512 + 512 + 512 + 4;
  for (int idx = blockIdx.x * blockDim.x + threadIdx.x; idx < total;
       idx += gridDim.x * blockDim.x) {
    if (idx < N1) {
      int c = idx >> 11;           // / 2048
      int rem = idx & 2047;
      int gnt = rem >> 6, lane = rem & 63;
      int n = gnt * 16 + (lane & 15);
      int r = (n & 3) * 128 + (n >> 2);     // original gate row
      int kb = c * 32 + (lane >> 4) * 8;
      u16* dst = wfrag1 + (size_t)idx * 8;
      for (int jj = 0; jj < 8; ++jj) {
        int k = kb + jj;
        float x;
        if (k < 128)      x = Wih1[r * 132 + 4 + k];        // mem features
        else if (k < 256) x = Whh1[r * 128 + (k - 128)];    // h features
        else if (k < 260) x = Wih1[r * 132 + (k - 256)];    // x features
        else              x = 0.f;                          // pad
        dst[jj] = f2bf(x);
      }
    } else if (idx < N1 + N2) {
      int i2 = idx - N1;
      int c = i2 >> 11;
      int rem = i2 & 2047;
      int gnt = rem >> 6, lane = rem & 63;
      int n = gnt * 16 + (lane & 15);
      int r = (n & 3) * 128 + (n >> 2);
      int kb = c * 32 + (lane >> 4) * 8;
      u16* dst = wfrag2 + (size_t)i2 * 8;
      for (int jj = 0; jj < 8; ++jj) {
        int k = kb + jj;
        float x = (k < 128) ? Wih2[r * 128 + k] : Whh2[r * 128 + (k - 128)];
        dst[jj] = f2bf(x);
      }
    } else if (idx < N1 + N2 + 512) {
      int n = idx - (N1 + N2);
      int r = (n & 3) * 128 + (n >> 2);
      biasp1[n] = bih1[r] + bhh1[r];
    } else if (idx < N1 + N2 + 1024) {
      int n = idx - (N1 + N2 + 512);
      int r = (n & 3) * 128 + (n >> 2);
      biasp2[n] = bih2[r] + bhh2[r];
    } else if (idx < N1 + N2 + 1024 + 512) {
      int i = idx - (N1 + N2 + 1024);
      int y = i >> 7, k = i & 127;
      float acc = 0.f;
      for (int j = 0; j < 128; ++j) acc = fmaf(Wout[y * 128 + j], Wlat[j * 128 + k], acc);
      Wco[i] = acc;
    } else {
      int y = idx - (N1 + N2 + 1024 + 512);
      float acc = bout[y];
      for (int j = 0; j < 128; ++j) acc = fmaf(Wout[y * 128 + j], blat[j], acc);
      bco[y] = acc;
    }
  }
}

// ---------------------------------------------------------------------------
// initial states: hx=tanh(sfc@Ws1^T+bs1) (bf16), c1=tanh(sfc@Ws2^T+bs2) (f32),
// h2a=bf16(hx2), c2=cx2
// ---------------------------------------------------------------------------
__global__ void sfc_init_kernel(const float* __restrict__ sfc,
                                const float* __restrict__ Ws1, const float* __restrict__ bs1,
                                const float* __restrict__ Ws2, const float* __restrict__ bs2,
                                const float* __restrict__ hx2, const float* __restrict__ cx2,
                                u16* __restrict__ hx, float* __restrict__ c1,
                                u16* __restrict__ h2a, float* __restrict__ c2) {
  int idx = blockIdx.x * 256 + threadIdx.x;
  if (idx >= B_ * H_) return;
  int b = idx >> 7, j = idx & 127;
  float s0 = sfc[b * 3 + 0], s1 = sfc[b * 3 + 1], s2 = sfc[b * 3 + 2];
  float a1 = fmaf(s2, Ws1[j * 3 + 2], fmaf(s1, Ws1[j * 3 + 1], fmaf(s0, Ws1[j * 3 + 0], bs1[j])));
  float a2 = fmaf(s2, Ws2[j * 3 + 2], fmaf(s1, Ws2[j * 3 + 1], fmaf(s0, Ws2[j * 3 + 0], bs2[j])));
  hx[idx] = f2bf(tanh_f(a1));
  c1[idx] = tanh_f(a2);
  h2a[idx] = f2bf(hx2[idx]);
  c2[idx] = cx2[idx];
}

__global__ void init_out_kernel(float* __restrict__ out, const float* __restrict__ bco) {
  int idx = blockIdx.x * 256 + threadIdx.x;
  if (idx >= B_ * T_) return;
  float4 b4 = *(const float4*)bco;
  ((float4*)out)[idx] = b4;
}

__global__ void sfc_out_kernel(const u16* __restrict__ h2, const float* __restrict__ Wsfc,
                               const float* __restrict__ bsfc, float* __restrict__ out_sfc) {
  int b = blockIdx.x * 256 + threadIdx.x;
  if (b >= B_) return;
  float a0 = bsfc[0], a1 = bsfc[1], a2 = bsfc[2];
  for (int j = 0; j < 128; ++j) {
    float h = bf2f(h2[(size_t)b * 128 + j]);
    a0 = fmaf(Wsfc[j], h, a0);
    a1 = fmaf(Wsfc[128 + j], h, a1);
    a2 = fmaf(Wsfc[256 + j], h, a2);
  }
  out_sfc[b * 3 + 0] = a0;
  out_sfc[b * 3 + 1] = a1;
  out_sfc[b * 3 + 2] = a2;
}

// ---------------------------------------------------------------------------
// Fused LSTM step. Grid (256,4), 256 threads = 4 waves, wave tile 32x64.
// C tile per block: 64 rows x 128 (permuted gate cols, i.e. 32 j's).
// LAYER 1: A = [mem(128) | h(128) | x(4) | pad] K=288, writes r1 slab.
// LAYER 2: A = [r1(128) | h(128)] K=256, fused Wco-out atomics.
// ---------------------------------------------------------------------------
template <int LAYER, int NC>
__global__ __launch_bounds__(256, 4) void lstm_step_kernel(
    const u16* __restrict__ wfrag, const float4* __restrict__ biasp4,
    const float* __restrict__ xsrc,    // L1: inputs_main + (59-s)*4, row stride 240
    const float* __restrict__ memsrc,  // L1: rnn1_mem0 + s*128, row stride 7680
    const u16* __restrict__ insrc,     // L2: r1 slab [B][128]
    const u16* __restrict__ hprev,     // [B][128] bf16
    float* __restrict__ cstate,        // [B][128] f32
    u16* __restrict__ hout,            // [B][128] bf16
    const float* __restrict__ Wco,     // [4][128]
    float* __restrict__ outp)          // out + t*4, row stride 240
{
  __shared__ __align__(16) u16 As[64 * 296];
  const int tid = threadIdx.x;
  const int mb = blockIdx.x;  // 0..255
  const int nb = blockIdx.y;  // 0..3
  const int row0 = mb * 64;

  // ---- stage A tile to LDS (row-major, stride 296 bf16) ----
  if (LAYER == 1) {
    for (int f = tid; f < 2048; f += 256) {  // mem: 64 rows x 32 float4
      int m = f >> 5, i = f & 31;
      float4 v = ((const float4*)(memsrc + (size_t)(row0 + m) * (T_ * H_)))[i];
      *(ushort4*)&As[m * 296 + i * 4] =
          make_ushort4(f2bf(v.x), f2bf(v.y), f2bf(v.z), f2bf(v.w));
    }
    for (int f = tid; f < 1024; f += 256) {  // h: 64 rows x 16 uint4
      int m = f >> 4, i = f & 15;
      uint4 v = ((const uint4*)(hprev + (size_t)(row0 + m) * H_))[i];
      *(uint4*)&As[m * 296 + 128 + i * 8] = v;
    }
    if (tid < 64) {  // x (4 feats) + zero pad to 288
      int m = tid;
      float4 v = *(const float4*)(xsrc + (size_t)(row0 + m) * (T_ * 4));
      *(ushort4*)&As[m * 296 + 256] =
          make_ushort4(f2bf(v.x), f2bf(v.y), f2bf(v.z), f2bf(v.w));
      ushort4 z4 = make_ushort4(0, 0, 0, 0);
#pragma unroll
      for (int i = 0; i < 7; ++i) *(ushort4*)&As[m * 296 + 260 + i * 4] = z4;
    }
  } else {
    for (int f = tid; f < 1024; f += 256) {  // r1 input
      int m = f >> 4, i = f & 15;
      uint4 v = ((const uint4*)(insrc + (size_t)(row0 + m) * H_))[i];
      *(uint4*)&As[m * 296 + i * 8] = v;
    }
    for (int f = tid; f < 1024; f += 256) {  // h
      int m = f >> 4, i = f & 15;
      uint4 v = ((const uint4*)(hprev + (size_t)(row0 + m) * H_))[i];
      *(uint4*)&As[m * 296 + 128 + i * 8] = v;
    }
  }
  __syncthreads();

  const int lane = tid & 63;
  const int w = tid >> 6;
  const int wm = w >> 1, wn = w & 1;
  const int lr = lane & 15, lq = lane >> 4;

  f32x4 acc[2][4];
#pragma unroll
  for (int mt = 0; mt < 2; ++mt)
#pragma unroll
    for (int nt = 0; nt < 4; ++nt) acc[mt][nt] = (f32x4){0.f, 0.f, 0.f, 0.f};

  const u16* abase = As + (wm * 32 + lr) * 296 + lq * 8;
  const u16* bbase = wfrag + ((size_t)((nb * 8 + wn * 4) * 64 + lane)) * 8;

#pragma unroll
  for (int c = 0; c < NC; ++c) {
    bf16x8 af[2], bfr[4];
#pragma unroll
    for (int mt = 0; mt < 2; ++mt)
      af[mt] = *(const bf16x8*)(abase + mt * (16 * 296) + c * 32);
#pragma unroll
    for (int nt = 0; nt < 4; ++nt)
      bfr[nt] = *(const bf16x8*)(bbase + (size_t)c * 16384 + nt * 512);
#pragma unroll
    for (int mt = 0; mt < 2; ++mt)
#pragma unroll
      for (int nt = 0; nt < 4; ++nt)
        acc[mt][nt] =
            __builtin_amdgcn_mfma_f32_16x16x32_bf16(af[mt], bfr[nt], acc[mt][nt], 0, 0, 0);
  }

  // ---- epilogue: z exchange through LDS (reuse A buffer), fused cell ----
  __syncthreads();
  float* zs = (float*)As;  // [64][132]
#pragma unroll
  for (int mt = 0; mt < 2; ++mt) {
    int r0 = wm * 32 + mt * 16 + lq * 4;
#pragma unroll
    for (int nt = 0; nt < 4; ++nt) {
      int nn = wn * 64 + nt * 16 + lr;
#pragma unroll
      for (int g = 0; g < 4; ++g) zs[(r0 + g) * 132 + nn] = acc[mt][nt][g];
    }
  }
  __syncthreads();

  {
    const int m = tid >> 2;
    const int qtr = tid & 3;
    const size_t gb = (size_t)row0 + m;
    float po0 = 0.f, po1 = 0.f, po2 = 0.f, po3 = 0.f;
#pragma unroll
    for (int jj = 0; jj < 8; ++jj) {
      int jl = qtr * 8 + jj;      // local j 0..31
      int jg = nb * 32 + jl;      // global j 0..127
      float4 z = *(const float4*)&zs[m * 132 + jl * 4];
      float4 bz = biasp4[jg];
      float gi = sigm(z.x + bz.x);
      float gf = sigm(z.y + bz.y);
      float gg = tanh_f(z.z + bz.z);
      float go = sigm(z.w + bz.w);
      size_t ci = gb * H_ + jg;
      float c = gf * cstate[ci] + gi * gg;
      cstate[ci] = c;
      float h = go * tanh_f(c);
      hout[ci] = f2bf(h);
      if (LAYER == 2) {
        po0 = fmaf(Wco[jg], h, po0);
        po1 = fmaf(Wco[128 + jg], h, po1);
        po2 = fmaf(Wco[256 + jg], h, po2);
        po3 = fmaf(Wco[384 + jg], h, po3);
      }
    }
    if (LAYER == 2) {
      float* op = outp + gb * 240;
      atomicAdd(op + 0, po0);
      atomicAdd(op + 1, po1);
      atomicAdd(op + 2, po2);
      atomicAdd(op + 3, po3);
    }
  }
}

// ---------------------------------------------------------------------------
extern "C" void kernel_launch(void* const* d_in, const int* in_sizes, int n_in,
                              void* d_out, int out_size, void* d_ws, size_t ws_size,
                              hipStream_t stream) {
  (void)in_sizes; (void)n_in; (void)out_size;
  const float* inputs_main = (const float*)d_in[0];
  const float* inputs_sfc  = (const float*)d_in[1];
  const float* rnn1_mem0   = (const float*)d_in[2];
  const float* hx2         = (const float*)d_in[3];
  const float* cx2         = (const float*)d_in[4];
  const float* Ws1  = (const float*)d_in[5];
  const float* bs1  = (const float*)d_in[6];
  const float* Ws2  = (const float*)d_in[7];
  const float* bs2  = (const float*)d_in[8];
  const float* Wih1 = (const float*)d_in[9];
  const float* Whh1 = (const float*)d_in[10];
  const float* bih1 = (const float*)d_in[11];
  const float* bhh1 = (const float*)d_in[12];
  const float* Wih2 = (const float*)d_in[13];
  const float* Whh2 = (const float*)d_in[14];
  const float* bih2 = (const float*)d_in[15];
  const float* bhh2 = (const float*)d_in[16];
  const float* Wlat = (const float*)d_in[17];
  const float* blat = (const float*)d_in[18];
  const float* Wout = (const float*)d_in[19];
  const float* bout = (const float*)d_in[20];
  const float* Wsfc = (const float*)d_in[21];
  const float* bsfc = (const float*)d_in[22];

  float* out = (float*)d_out;                        // [B,60,4]
  float* out_sfc = out + (size_t)B_ * T_ * 4;        // [B,3]

  char* p = (char*)d_ws;
  u16* wfrag1  = (u16*)p;  p += 294912;              // 9*32*64*8 bf16
  u16* wfrag2  = (u16*)p;  p += 262144;              // 8*32*64*8 bf16
  float* biasp1 = (float*)p; p += 2048;
  float* biasp2 = (float*)p; p += 2048;
  float* Wco    = (float*)p; p += 2048;
  float* bco    = (float*)p; p += 256;
  u16* hx      = (u16*)p;  p += (size_t)B_ * H_ * 2;
  float* c1    = (float*)p; p += (size_t)B_ * H_ * 4;
  float* c2    = (float*)p; p += (size_t)B_ * H_ * 4;
  u16* h2buf[2];
  h2buf[0] = (u16*)p; p += (size_t)B_ * H_ * 2;
  h2buf[1] = (u16*)p; p += (size_t)B_ * H_ * 2;
  u16* r1buf = (u16*)p; p += (size_t)T_ * B_ * H_ * 2;
  if ((size_t)(p - (char*)d_ws) > ws_size) return;   // insufficient workspace

  prep_kernel<<<152, 256, 0, stream>>>(Wih1, Whh1, bih1, bhh1, Wih2, Whh2, bih2, bhh2,
                                       Wlat, blat, Wout, bout,
                                       wfrag1, wfrag2, biasp1, biasp2, Wco, bco);
  sfc_init_kernel<<<(B_ * H_) / 256, 256, 0, stream>>>(inputs_sfc, Ws1, bs1, Ws2, bs2,
                                                       hx2, cx2, hx, c1, h2buf[0], c2);
  init_out_kernel<<<(B_ * T_) / 256, 256, 0, stream>>>(out, bco);

  dim3 grid(256, 4);
  for (int s = 0; s < T_; ++s) {
    const u16* hp = (s == 0) ? hx : (r1buf + (size_t)(s - 1) * B_ * H_);
    lstm_step_kernel<1, 9><<<grid, 256, 0, stream>>>(
        wfrag1, (const float4*)biasp1,
        inputs_main + (size_t)(T_ - 1 - s) * 4,   // x_flip[:, s] = inputs_main[:, 59-s]
        rnn1_mem0 + (size_t)s * H_,
        nullptr, hp, c1,
        r1buf + (size_t)s * B_ * H_,              // h out doubles as r1 slab s
        nullptr, nullptr);
  }
  for (int t = 0; t < T_; ++t) {
    lstm_step_kernel<2, 8><<<grid, 256, 0, stream>>>(
        wfrag2, (const float4*)biasp2,
        nullptr, nullptr,
        r1buf + (size_t)(T_ - 1 - t) * B_ * H_,   // r1[:, t] = r1_tmp[:, 59-t]
        h2buf[t & 1], c2, h2buf[(t + 1) & 1],
        Wco, out + (size_t)t * 4);
  }
  // final h2 is in h2buf[0] after 60 steps
  sfc_out_kernel<<<B_ / 256, 256, 0, stream>>>(h2buf[0], Wsfc, bsfc, out_sfc);
}

// Round 3
// 1878.359 us; speedup vs baseline: 3.0698x; 3.0698x over previous
//
#include <hip/hip_runtime.h>

#define B_ 16384
#define T_ 60
#define H_ 128
#define LDST 296   // A-tile row stride in u16 (K=288 + 8 pad)

typedef unsigned short u16;
typedef short bf16x8 __attribute__((ext_vector_type(8)));
typedef float f32x4 __attribute__((ext_vector_type(4)));

__device__ __forceinline__ u16 f2bf(float f) {
  union { float f; unsigned int u; } v; v.f = f;
  unsigned int r = v.u + 0x7fffu + ((v.u >> 16) & 1u);
  return (u16)(r >> 16);
}
__device__ __forceinline__ float bf2f(u16 b) {
  union { unsigned int u; float f; } v; v.u = ((unsigned int)b) << 16;
  return v.f;
}
__device__ __forceinline__ float sigm(float x) {
  return __builtin_amdgcn_rcpf(1.f + __expf(-x));
}
__device__ __forceinline__ float tanh_f(float x) {
  return 1.f - 2.f * __builtin_amdgcn_rcpf(1.f + __expf(2.f * x));
}

// ---------------------------------------------------------------------------
// prep: pack weights into MFMA B-fragment order, n = torch gate row (g*128+j).
// wfrag[((c*32+nt)*64+lane)*8+jj] = W[k = c*32+(lane>>4)*8+jj][n = nt*16+(lane&15)]
// Also fold Wout@Wlat -> Wco [4][128], bco[4].
// ---------------------------------------------------------------------------
__global__ void prep_kernel(const float* __restrict__ Wih1, const float* __restrict__ Whh1,
                            const float* __restrict__ Wih2, const float* __restrict__ Whh2,
                            const float* __restrict__ Wlat, const float* __restrict__ blat,
                            const float* __restrict__ Wout, const float* __restrict__ bout,
                            u16* __restrict__ wfrag1, u16* __restrict__ wfrag2,
                            float* __restrict__ Wco, float* __restrict__ bco) {
  const int N1 = 9 * 32 * 64;   // 18432 lane-groups of 8
  const int N2 = 8 * 32 * 64;   // 16384
  const int total = N1 + N2 + 512 + 4;
  for (int idx = blockIdx.x * blockDim.x + threadIdx.x; idx < total;
       idx += gridDim.x * blockDim.x) {
    if (idx < N1) {
      int c = idx >> 11;
      int rem = idx & 2047;
      int nt = rem >> 6, lane = rem & 63;
      int n = nt * 16 + (lane & 15);        // torch gate row directly
      int kb = c * 32 + (lane >> 4) * 8;
      u16* dst = wfrag1 + (size_t)idx * 8;
      for (int jj = 0; jj < 8; ++jj) {
        int k = kb + jj;
        float x;
        if (k < 128)      x = Wih1[n * 132 + 4 + k];        // mem features
        else if (k < 256) x = Whh1[n * 128 + (k - 128)];    // h features
        else if (k < 260) x = Wih1[n * 132 + (k - 256)];    // x features
        else              x = 0.f;                          // pad
        dst[jj] = f2bf(x);
      }
    } else if (idx < N1 + N2) {
      int i2 = idx - N1;
      int c = i2 >> 11;
      int rem = i2 & 2047;
      int nt = rem >> 6, lane = rem & 63;
      int n = nt * 16 + (lane & 15);
      int kb = c * 32 + (lane >> 4) * 8;
      u16* dst = wfrag2 + (size_t)i2 * 8;
      for (int jj = 0; jj < 8; ++jj) {
        int k = kb + jj;
        float x = (k < 128) ? Wih2[n * 128 + k] : Whh2[n * 128 + (k - 128)];
        dst[jj] = f2bf(x);
      }
    } else if (idx < N1 + N2 + 512) {
      int i = idx - (N1 + N2);
      int y = i >> 7, k = i & 127;
      float acc = 0.f;
      for (int j = 0; j < 128; ++j) acc = fmaf(Wout[y * 128 + j], Wlat[j * 128 + k], acc);
      Wco[i] = acc;
    } else {
      int y = idx - (N1 + N2 + 512);
      float acc = bout[y];
      for (int j = 0; j < 128; ++j) acc = fmaf(Wout[y * 128 + j], blat[j], acc);
      bco[y] = acc;
    }
  }
}

// ---------------------------------------------------------------------------
// MFMA core: A from LDS (64 x K tile, stride LDST), B frags from global (L2-hot).
// Wave w covers j-slice [w*16,w*16+16): gate-tile g at n-tile g*8+w.
// ---------------------------------------------------------------------------
template <int NC>
__device__ __forceinline__ void do_mfma(const u16* __restrict__ As,
                                        const u16* __restrict__ wfrag,
                                        int w, int lane, f32x4 acc[4][4]) {
  const int lr = lane & 15, lq = lane >> 4;
  const u16* ab = As + lr * LDST + lq * 8;
  const u16* bb = wfrag + (size_t)(w * 512 + lane * 8);  // g stride 4096, c stride 16384
  bf16x8 bcur[4];
#pragma unroll
  for (int g = 0; g < 4; ++g) bcur[g] = *(const bf16x8*)(bb + g * 4096);
#pragma unroll
  for (int c = 0; c < NC; ++c) {
    bf16x8 bnxt[4];
    const int cn = (c + 1 < NC) ? c + 1 : c;
#pragma unroll
    for (int g = 0; g < 4; ++g)
      bnxt[g] = *(const bf16x8*)(bb + (size_t)cn * 16384 + g * 4096);
    bf16x8 af[4];
#pragma unroll
    for (int mt = 0; mt < 4; ++mt)
      af[mt] = *(const bf16x8*)(ab + mt * (16 * LDST) + c * 32);
#pragma unroll
    for (int g = 0; g < 4; ++g)
#pragma unroll
      for (int mt = 0; mt < 4; ++mt)
        acc[mt][g] = __builtin_amdgcn_mfma_f32_16x16x32_bf16(af[mt], bcur[g], acc[mt][g], 0, 0, 0);
#pragma unroll
    for (int g = 0; g < 4; ++g) bcur[g] = bnxt[g];
  }
}

// cell update fully in-register: acc[mt][gate][reg], gates of a j are in-lane.
__device__ __forceinline__ void cell_update(f32x4 acc[4][4], float4 bz,
                                            float* __restrict__ cr, u16* __restrict__ hb) {
#pragma unroll
  for (int mt = 0; mt < 4; ++mt)
#pragma unroll
    for (int r = 0; r < 4; ++r) {
      int idx = mt * 4 + r;
      float gi = sigm(acc[mt][0][r] + bz.x);
      float gf = sigm(acc[mt][1][r] + bz.y);
      float gg = tanh_f(acc[mt][2][r] + bz.z);
      float go = sigm(acc[mt][3][r] + bz.w);
      float c = gf * cr[idx] + gi * gg;
      cr[idx] = c;
      hb[idx] = f2bf(go * tanh_f(c));
    }
}

// dot of 8 bf16 h values (packed uint4) with 8 fp32 weights
__device__ __forceinline__ float dot8w(uint4 hu, const float* __restrict__ wp, float a) {
  const unsigned* h = (const unsigned*)&hu;
#pragma unroll
  for (int i = 0; i < 4; ++i) {
    union { unsigned u; float f; } hl, hh;
    hl.u = h[i] << 16; hh.u = h[i] & 0xffff0000u;
    a = fmaf(hl.f, wp[2 * i], a);
    a = fmaf(hh.f, wp[2 * i + 1], a);
  }
  return a;
}

// ---------------------------------------------------------------------------
// Persistent kernel: 256 blocks x 512 threads. Block owns 64 batch rows for
// all 120 steps. h in LDS A-tile, c in registers, r1 slabs block-private.
// ---------------------------------------------------------------------------
__global__ __launch_bounds__(512, 2) void rnn_persist(
    const float* __restrict__ inputs_main, const float* __restrict__ inputs_sfc,
    const float* __restrict__ rnn1_mem0, const float* __restrict__ hx2,
    const float* __restrict__ cx2,
    const float* __restrict__ Ws1, const float* __restrict__ bs1,
    const float* __restrict__ Ws2, const float* __restrict__ bs2,
    const float* __restrict__ bih1, const float* __restrict__ bhh1,
    const float* __restrict__ bih2, const float* __restrict__ bhh2,
    const float* __restrict__ Wsfc, const float* __restrict__ bsfc,
    const u16* __restrict__ wfrag1, const u16* __restrict__ wfrag2,
    const float* __restrict__ Wco, const float* __restrict__ bco,
    u16* __restrict__ r1buf, float* __restrict__ out, float* __restrict__ out_sfc) {
  __shared__ __align__(16) u16 As[64 * LDST];   // 37888 B
  __shared__ __align__(16) float WcoS[4 * 132]; // fp32 for epilogue accuracy
  __shared__ __align__(16) float WsfcS[3 * 132];

  const int tid = threadIdx.x;
  const int w = tid >> 6, lane = tid & 63, lr = lane & 15, lq = lane >> 4;
  const int jg = w * 16 + lr;                   // this lane's j (0..127)
  const size_t row0 = (size_t)blockIdx.x * 64;

  // hoisted per-lane constants
  const float4 bz1 = make_float4(bih1[jg] + bhh1[jg], bih1[128 + jg] + bhh1[128 + jg],
                                 bih1[256 + jg] + bhh1[256 + jg], bih1[384 + jg] + bhh1[384 + jg]);
  const float4 bz2 = make_float4(bih2[jg] + bhh2[jg], bih2[128 + jg] + bhh2[128 + jg],
                                 bih2[256 + jg] + bhh2[256 + jg], bih2[384 + jg] + bhh2[384 + jg]);
  const float bcoy = bco[tid & 3];

  // Wco/Wsfc -> LDS fp32 (padded stride 132)
  if (tid < 512) WcoS[(tid >> 7) * 132 + (tid & 127)] = Wco[tid];
  if (tid < 384) WsfcS[(tid >> 7) * 132 + (tid & 127)] = Wsfc[tid];

  // zero k256..287 region once (x overwrites 256..259; pad stays 0)
#pragma unroll
  for (int kk = 0; kk < 4; ++kk) {
    int f = tid + kk * 512;
    As[(f >> 5) * LDST + 256 + (f & 31)] = 0;
  }

  float cr[16];
  u16 hb[16];
  // init h1 = tanh(sfc@Ws1^T+bs1) -> LDS h-region, c1 = tanh(sfc@Ws2^T+bs2) -> regs
  {
    float w1a = Ws1[jg * 3], w1b = Ws1[jg * 3 + 1], w1c = Ws1[jg * 3 + 2], b1 = bs1[jg];
    float w2a = Ws2[jg * 3], w2b = Ws2[jg * 3 + 1], w2c = Ws2[jg * 3 + 2], b2 = bs2[jg];
#pragma unroll
    for (int mt = 0; mt < 4; ++mt)
#pragma unroll
      for (int r = 0; r < 4; ++r) {
        int rl = mt * 16 + lq * 4 + r;
        const float* sp = inputs_sfc + (row0 + rl) * 3;
        float s0 = sp[0], s1 = sp[1], s2 = sp[2];
        float h0 = tanh_f(fmaf(s2, w1c, fmaf(s1, w1b, fmaf(s0, w1a, b1))));
        cr[mt * 4 + r] = tanh_f(fmaf(s2, w2c, fmaf(s1, w2b, fmaf(s0, w2a, b2))));
        As[rl * LDST + 128 + jg] = f2bf(h0);
      }
  }
  // stage mem_0 (k0..127) and x_0 (k256..259)
#pragma unroll
  for (int kk = 0; kk < 4; ++kk) {
    int f = tid + kk * 512, row = f >> 5, i = f & 31;
    float4 v = *(const float4*)(rnn1_mem0 + (row0 + row) * (T_ * H_) + i * 4);
    *(ushort4*)&As[row * LDST + i * 4] =
        make_ushort4(f2bf(v.x), f2bf(v.y), f2bf(v.z), f2bf(v.w));
  }
  if (tid < 64) {
    float4 v = *(const float4*)(inputs_main + ((row0 + tid) * T_ + 59) * 4);
    *(ushort4*)&As[tid * LDST + 256] = make_ushort4(f2bf(v.x), f2bf(v.y), f2bf(v.z), f2bf(v.w));
  }
  __syncthreads();

  // ================= LSTM1: s = 0..59 =================
#pragma unroll 1
  for (int s = 0; s < T_; ++s) {
    const int sn = (s < 59) ? s + 1 : 59;
    float4 mv[4];
#pragma unroll
    for (int kk = 0; kk < 4; ++kk) {
      int f = tid + kk * 512;
      mv[kk] = *(const float4*)(rnn1_mem0 + (row0 + (f >> 5)) * (T_ * H_) + sn * 128 + (f & 31) * 4);
    }
    float4 xv = make_float4(0, 0, 0, 0);
    if (tid < 64) xv = *(const float4*)(inputs_main + ((row0 + tid) * T_ + (59 - sn)) * 4);

    f32x4 acc[4][4];
#pragma unroll
    for (int mt = 0; mt < 4; ++mt)
#pragma unroll
      for (int g = 0; g < 4; ++g) acc[mt][g] = (f32x4){0.f, 0.f, 0.f, 0.f};
    do_mfma<9>(As, wfrag1, w, lane, acc);
    cell_update(acc, bz1, cr, hb);
    // r1 slab store (block-private rows)
#pragma unroll
    for (int mt = 0; mt < 4; ++mt)
#pragma unroll
      for (int r = 0; r < 4; ++r)
        r1buf[((size_t)s * B_ + row0 + mt * 16 + lq * 4 + r) * H_ + jg] = hb[mt * 4 + r];
    __syncthreads();
    // write new h + next mem/x into A-tile
#pragma unroll
    for (int mt = 0; mt < 4; ++mt)
#pragma unroll
      for (int r = 0; r < 4; ++r)
        As[(mt * 16 + lq * 4 + r) * LDST + 128 + jg] = hb[mt * 4 + r];
#pragma unroll
    for (int kk = 0; kk < 4; ++kk) {
      int f = tid + kk * 512, row = f >> 5, i = f & 31;
      *(ushort4*)&As[row * LDST + i * 4] =
          make_ushort4(f2bf(mv[kk].x), f2bf(mv[kk].y), f2bf(mv[kk].z), f2bf(mv[kk].w));
    }
    if (tid < 64)
      *(ushort4*)&As[tid * LDST + 256] = make_ushort4(f2bf(xv.x), f2bf(xv.y), f2bf(xv.z), f2bf(xv.w));
    __syncthreads();
  }

  // ============ transition: r1[t=0] = h-region -> k0; init h2/c2 ============
  {
    // FULL-WIDTH copy: 2 x uint4 per thread = 64 rows x 128 u16 (R2 bug: half)
    uint4 cv[2];
#pragma unroll
    for (int kk = 0; kk < 2; ++kk) {
      int f = tid + kk * 512;
      cv[kk] = *(const uint4*)&As[(f >> 4) * LDST + 128 + (f & 15) * 8];
    }
    __syncthreads();
#pragma unroll
    for (int kk = 0; kk < 2; ++kk) {
      int f = tid + kk * 512;
      *(uint4*)&As[(f >> 4) * LDST + (f & 15) * 8] = cv[kk];
    }
#pragma unroll
    for (int mt = 0; mt < 4; ++mt)
#pragma unroll
      for (int r = 0; r < 4; ++r) {
        int rl = mt * 16 + lq * 4 + r;
        size_t gi = (row0 + rl) * H_ + jg;
        cr[mt * 4 + r] = cx2[gi];
        As[rl * LDST + 128 + jg] = f2bf(hx2[gi]);
      }
    __syncthreads();
  }

  // ================= LSTM2: t = 0..59 (input slab = 59-t) =================
#pragma unroll 1
  for (int t = 0; t < T_; ++t) {
    const int slabn = (t < 59) ? (58 - t) : 0;
    uint4 rv[2];
#pragma unroll
    for (int kk = 0; kk < 2; ++kk) {
      int f = tid + kk * 512;
      rv[kk] = *(const uint4*)(r1buf + ((size_t)slabn * B_ + row0 + (f >> 4)) * H_ + (f & 15) * 8);
    }
    f32x4 acc[4][4];
#pragma unroll
    for (int mt = 0; mt < 4; ++mt)
#pragma unroll
      for (int g = 0; g < 4; ++g) acc[mt][g] = (f32x4){0.f, 0.f, 0.f, 0.f};
    do_mfma<8>(As, wfrag2, w, lane, acc);
    cell_update(acc, bz2, cr, hb);
    __syncthreads();
#pragma unroll
    for (int mt = 0; mt < 4; ++mt)
#pragma unroll
      for (int r = 0; r < 4; ++r)
        As[(mt * 16 + lq * 4 + r) * LDST + 128 + jg] = hb[mt * 4 + r];
#pragma unroll
    for (int kk = 0; kk < 2; ++kk) {
      int f = tid + kk * 512;
      *(uint4*)&As[(f >> 4) * LDST + (f & 15) * 8] = rv[kk];
    }
    __syncthreads();
    // fused out = h2 @ Wco^T + bco  (quarter of threads reduce from LDS h)
    if (tid < 256) {
      int row = tid >> 2, y = tid & 3;
      float a = bcoy;
      const u16* hrow = As + row * LDST + 128;
      const float* wrow = WcoS + y * 132;
#pragma unroll
      for (int sg = 0; sg < 16; ++sg)
        a = dot8w(*(const uint4*)(hrow + sg * 8), wrow + sg * 8, a);
      out[((row0 + row) * T_ + t) * 4 + y] = a;
    }
    if (t == 59 && tid >= 256) {
      int q = tid - 256;
      int row = q >> 2, y = q & 3;
      if (y < 3) {
        float a = bsfc[y];
        const u16* hrow = As + row * LDST + 128;
        const float* wrow = WsfcS + y * 132;
#pragma unroll
        for (int sg = 0; sg < 16; ++sg)
          a = dot8w(*(const uint4*)(hrow + sg * 8), wrow + sg * 8, a);
        out_sfc[(row0 + row) * 3 + y] = a;
      }
    }
  }
}

// ---------------------------------------------------------------------------
extern "C" void kernel_launch(void* const* d_in, const int* in_sizes, int n_in,
                              void* d_out, int out_size, void* d_ws, size_t ws_size,
                              hipStream_t stream) {
  (void)in_sizes; (void)n_in; (void)out_size;
  const float* inputs_main = (const float*)d_in[0];
  const float* inputs_sfc  = (const float*)d_in[1];
  const float* rnn1_mem0   = (const float*)d_in[2];
  const float* hx2         = (const float*)d_in[3];
  const float* cx2         = (const float*)d_in[4];
  const float* Ws1  = (const float*)d_in[5];
  const float* bs1  = (const float*)d_in[6];
  const float* Ws2  = (const float*)d_in[7];
  const float* bs2  = (const float*)d_in[8];
  const float* Wih1 = (const float*)d_in[9];
  const float* Whh1 = (const float*)d_in[10];
  const float* bih1 = (const float*)d_in[11];
  const float* bhh1 = (const float*)d_in[12];
  const float* Wih2 = (const float*)d_in[13];
  const float* Whh2 = (const float*)d_in[14];
  const float* bih2 = (const float*)d_in[15];
  const float* bhh2 = (const float*)d_in[16];
  const float* Wlat = (const float*)d_in[17];
  const float* blat = (const float*)d_in[18];
  const float* Wout = (const float*)d_in[19];
  const float* bout = (const float*)d_in[20];
  const float* Wsfc = (const float*)d_in[21];
  const float* bsfc = (const float*)d_in[22];

  float* out = (float*)d_out;                        // [B,60,4]
  float* out_sfc = out + (size_t)B_ * T_ * 4;        // [B,3]

  char* p = (char*)d_ws;
  u16* wfrag1 = (u16*)p; p += 294912;                // 9*32*64*8 bf16
  u16* wfrag2 = (u16*)p; p += 262144;                // 8*32*64*8 bf16
  float* Wco  = (float*)p; p += 2048;
  float* bco  = (float*)p; p += 64;
  u16* r1buf  = (u16*)p; p += (size_t)T_ * B_ * H_ * 2;
  if ((size_t)(p - (char*)d_ws) > ws_size) return;

  prep_kernel<<<139, 256, 0, stream>>>(Wih1, Whh1, Wih2, Whh2, Wlat, blat, Wout, bout,
                                       wfrag1, wfrag2, Wco, bco);
  rnn_persist<<<256, 512, 0, stream>>>(inputs_main, inputs_sfc, rnn1_mem0, hx2, cx2,
                                       Ws1, bs1, Ws2, bs2,
                                       bih1, bhh1, bih2, bhh2, Wsfc, bsfc,
                                       wfrag1, wfrag2, Wco, bco,
                                       r1buf, out, out_sfc);
}